// Round 2
// baseline (106.429 us; speedup 1.0000x reference)
//
#include <hip/hip_runtime.h>
#include <hip/hip_bf16.h>

// GraphSAGE 2-layer forward, fp32.
// B=512, S0=25, S1=10, IN_DIM=256, HID=128 (concat->256), N_CLASSES=7.

constexpr int IN   = 256;
constexpr int HIDC = 128;   // per-branch hidden
constexpr int BM   = 16;    // rows per block in k_h1
constexpr int ROWS1 = 512 * 25;  // 12800

// ---------------- Kernel 1: h1 = relu([f1@Wx1+b, mean10(f2)@Wn1+b]) --------
// One block = BM rows, 512 threads (8 waves -> ~25 waves/CU at grid 800).
__global__ __launch_bounds__(512) void k_h1(
    const int* __restrict__ ids1, const int* __restrict__ ids2,
    const float* __restrict__ feats,
    const float* __restrict__ Wx, const float* __restrict__ bx,
    const float* __restrict__ Wn, const float* __restrict__ bn,
    float* __restrict__ h1)
{
    __shared__ float a0[BM][IN];
    __shared__ float a1[BM][IN];
    const int tid = threadIdx.x;
    const int r0  = blockIdx.x * BM;

    // ---- staging: 8 rows in parallel (64 threads/row, float4 = 1KB/row coalesced)
    const int sub = tid & 63;      // float4 index within row
    const int rg  = tid >> 6;      // 0..7
    #pragma unroll
    for (int i = 0; i < BM; i += 8) {
        const int rr = rg + i;
        const int r  = r0 + rr;
        const float4* s0 = (const float4*)(feats + (size_t)ids1[r] * IN);
        ((float4*)a0[rr])[sub] = s0[sub];
        float4 acc = make_float4(0.f, 0.f, 0.f, 0.f);
        #pragma unroll
        for (int kk = 0; kk < 10; ++kk) {
            const float4* p = (const float4*)(feats + (size_t)ids2[r * 10 + kk] * IN);
            const float4 v = p[sub];
            acc.x += v.x; acc.y += v.y; acc.z += v.z; acc.w += v.w;
        }
        acc.x *= 0.1f; acc.y *= 0.1f; acc.z *= 0.1f; acc.w *= 0.1f;
        ((float4*)a1[rr])[sub] = acc;
    }
    __syncthreads();

    // ---- compute: register-tiled GEMV, 4 rows x 2 cols per thread
    const int j  = tid & 127;
    const int g  = tid >> 7;            // row group 0..3
    const int c0 = 2 * j;               // output col pair {c0, c0+1} in [0,256)
    const bool nb = (c0 >= HIDC);       // neighbor branch?
    const int cc  = c0 & (HIDC - 1);
    const float* __restrict__ W  = nb ? Wn : Wx;
    const float  b0 = (nb ? bn : bx)[cc];
    const float  b1 = (nb ? bn : bx)[cc + 1];
    const float (* __restrict__ A)[IN] = nb ? a1 : a0;
    const float2* __restrict__ W2 = (const float2*)W;  // W[k*128+cc] -> W2[k*64 + cc/2]
    const int w2i = cc >> 1;

    float acc0[4], acc1[4];
    #pragma unroll
    for (int rr = 0; rr < 4; ++rr) { acc0[rr] = 0.f; acc1[rr] = 0.f; }

    for (int k = 0; k < IN; k += 4) {
        float4 av[4];
        #pragma unroll
        for (int rr = 0; rr < 4; ++rr)
            av[rr] = *(const float4*)&A[g * 4 + rr][k];   // wave-uniform -> broadcast
        #pragma unroll
        for (int kk = 0; kk < 4; ++kk) {
            const float2 w = W2[(size_t)(k + kk) * 64 + w2i];
            #pragma unroll
            for (int rr = 0; rr < 4; ++rr) {
                const float a = (&av[rr].x)[kk];
                acc0[rr] = fmaf(a, w.x, acc0[rr]);
                acc1[rr] = fmaf(a, w.y, acc1[rr]);
            }
        }
    }
    #pragma unroll
    for (int rr = 0; rr < 4; ++rr) {
        const int r = r0 + g * 4 + rr;
        float2 v;
        v.x = fmaxf(acc0[rr] + b0, 0.f);
        v.y = fmaxf(acc1[rr] + b1, 0.f);
        *(float2*)&h1[(size_t)r * (2 * HIDC) + c0] = v;
    }
}

// ---------------- Kernel 2: per output row, 512 threads ---------------------
// h0 = relu([f0@Wx1+b, mean25(f1)@Wn1+b]); g0 = [h0@Wx2+b, mean25(h1)@Wn2+b];
// out = normalize(g0) @ Wfc + bfc
__global__ __launch_bounds__(512) void k_out(
    const int* __restrict__ ids, const int* __restrict__ ids1,
    const float* __restrict__ feats, const float* __restrict__ h1,
    const float* __restrict__ Wx1, const float* __restrict__ bx1,
    const float* __restrict__ Wn1, const float* __restrict__ bn1,
    const float* __restrict__ Wx2, const float* __restrict__ bx2,
    const float* __restrict__ Wn2, const float* __restrict__ bn2,
    const float* __restrict__ Wfc, const float* __restrict__ bfc,
    float* __restrict__ out)
{
    __shared__ float x0[IN];
    __shared__ float m1[IN];
    __shared__ float mh[IN];
    __shared__ float h0[IN];
    __shared__ float g0[IN];
    __shared__ float partA[2][IN];
    __shared__ float partB[2][IN];
    __shared__ float red[8];
    __shared__ float fcred[7][4];
    const int i   = blockIdx.x;
    const int tid = threadIdx.x;
    const int c   = tid & 255;
    const int h   = tid >> 8;        // k-half / sample-half

    // ---- stage + partial means (sample dim split across halves: 13 + 12)
    float s = 0.f, sh = 0.f;
    for (int kk = h; kk < 25; kk += 2) {
        const int r = i * 25 + kk;
        s  += feats[(size_t)ids1[r] * IN + c];
        sh += h1[(size_t)r * IN + c];
    }
    if (h == 0) x0[c] = feats[(size_t)ids[i] * IN + c];
    partA[h][c] = s;
    partB[h][c] = sh;
    __syncthreads();
    if (h == 0) m1[c] = (partA[0][c] + partA[1][c]) * 0.04f;
    else        mh[c] = (partB[0][c] + partB[1][c]) * 0.04f;
    __syncthreads();

    const int  jj = c & 127;
    const bool nb = (c >= 128);
    // ---- layer 1, split-k (128 per half)
    {
        const float* __restrict__ W = nb ? Wn1 : Wx1;
        const float* __restrict__ X = nb ? m1 : x0;
        float acc = 0.f;
        #pragma unroll 4
        for (int k = h * 128; k < h * 128 + 128; ++k)
            acc = fmaf(X[k], W[(size_t)k * HIDC + jj], acc);
        partA[h][c] = acc;
    }
    __syncthreads();
    if (h == 0)
        h0[c] = fmaxf(partA[0][c] + partA[1][c] + (nb ? bn1 : bx1)[jj], 0.f);
    __syncthreads();
    // ---- layer 2, split-k (no activation)
    {
        const float* __restrict__ W = nb ? Wn2 : Wx2;
        const float* __restrict__ X = nb ? mh : h0;
        float acc = 0.f;
        #pragma unroll 4
        for (int k = h * 128; k < h * 128 + 128; ++k)
            acc = fmaf(X[k], W[(size_t)k * HIDC + jj], acc);
        partB[h][c] = acc;
    }
    __syncthreads();
    if (h == 0)
        g0[c] = partB[0][c] + partB[1][c] + (nb ? bn2 : bx2)[jj];
    __syncthreads();

    // ---- L2 norm: all 8 waves reduce (each c counted twice -> *0.5)
    {
        const float gv = g0[c];
        float sq = gv * gv;
        #pragma unroll
        for (int off = 32; off > 0; off >>= 1) sq += __shfl_down(sq, off);
        if ((tid & 63) == 0) red[tid >> 6] = sq;
    }
    __syncthreads();
    const float total = (red[0] + red[1] + red[2] + red[3] +
                         red[4] + red[5] + red[6] + red[7]) * 0.5f;
    const float inv = 1.f / fmaxf(sqrtf(total), 1e-12f);
    const float p = g0[c] * inv;

    // ---- fc: half 0 -> outputs 0..3, half 1 -> outputs 4..6
    const int qbase = h * 4;
    const int qn    = h ? 3 : 4;
    for (int q = qbase; q < qbase + qn; ++q) {
        float t = p * Wfc[(size_t)c * 7 + q];
        #pragma unroll
        for (int off = 32; off > 0; off >>= 1) t += __shfl_down(t, off);
        if ((tid & 63) == 0) fcred[q][(tid >> 6) & 3] = t;
    }
    __syncthreads();
    if (tid < 7) {
        out[(size_t)i * 7 + tid] =
            fcred[tid][0] + fcred[tid][1] + fcred[tid][2] + fcred[tid][3] + bfc[tid];
    }
}

extern "C" void kernel_launch(void* const* d_in, const int* in_sizes, int n_in,
                              void* d_out, int out_size, void* d_ws, size_t ws_size,
                              hipStream_t stream) {
    const int*   ids   = (const int*)d_in[0];
    const int*   ids1  = (const int*)d_in[1];
    const int*   ids2  = (const int*)d_in[2];
    const float* feats = (const float*)d_in[3];
    const float* Wx1   = (const float*)d_in[4];
    const float* bx1   = (const float*)d_in[5];
    const float* Wn1   = (const float*)d_in[6];
    const float* bn1   = (const float*)d_in[7];
    const float* Wx2   = (const float*)d_in[8];
    const float* bx2   = (const float*)d_in[9];
    const float* Wn2   = (const float*)d_in[10];
    const float* bn2   = (const float*)d_in[11];
    const float* Wfc   = (const float*)d_in[12];
    const float* bfc   = (const float*)d_in[13];
    float* out = (float*)d_out;
    float* h1  = (float*)d_ws;   // 12800 x 256 f32 = 13.1 MB

    k_h1<<<ROWS1 / BM, 512, 0, stream>>>(ids1, ids2, feats, Wx1, bx1, Wn1, bn1, h1);
    k_out<<<512, 512, 0, stream>>>(ids, ids1, feats, h1,
                                   Wx1, bx1, Wn1, bn1,
                                   Wx2, bx2, Wn2, bn2,
                                   Wfc, bfc, out);
}

// Round 3
// 94.425 us; speedup vs baseline: 1.1271x; 1.1271x over previous
//
#include <hip/hip_runtime.h>
#include <hip/hip_bf16.h>

// GraphSAGE 2-layer forward, fp32.
// B=512, S0=25, S1=10, IN_DIM=256, HID=128 (concat->256), N_CLASSES=7.

constexpr int IN   = 256;
constexpr int HIDC = 128;   // per-branch hidden
constexpr int BM   = 16;    // rows per block in k_gemm
constexpr int ROWS1 = 512 * 25;  // 12800

// ---------------- Kernel A: m2[r] = mean10(f2 rows) -------------------------
// One wave per row: 64 lanes x float4 = 1KB row. 10 independent gathers/wave.
// Grid 1600 x 512thr = 12800 waves; no LDS -> max occupancy, max MLP.
__global__ __launch_bounds__(512) void k_mean(
    const int* __restrict__ ids2, const float* __restrict__ feats,
    float* __restrict__ m2)
{
    const int wave = threadIdx.x >> 6;
    const int lane = threadIdx.x & 63;
    const int r    = blockIdx.x * 8 + wave;
    const int base = r * 10;
    float4 acc = make_float4(0.f, 0.f, 0.f, 0.f);
    #pragma unroll
    for (int kk = 0; kk < 10; ++kk) {
        const float4* p = (const float4*)(feats + (size_t)ids2[base + kk] * IN);
        const float4 v = p[lane];
        acc.x += v.x; acc.y += v.y; acc.z += v.z; acc.w += v.w;
    }
    acc.x *= 0.1f; acc.y *= 0.1f; acc.z *= 0.1f; acc.w *= 0.1f;
    ((float4*)(m2 + (size_t)r * IN))[lane] = acc;
}

// ---------------- Kernel B: h1 = relu([f1@Wx1+b, m2@Wn1+b]) -----------------
// BM=16 rows/block, 256 threads, 8 rows x 2 cols per thread (W L2 traffic
// = 420 MB total; rows-per-thread is the lever that controls it).
// Writes h1 IN-PLACE over m2 (same [12800][256] ws buffer; row-block local).
__global__ __launch_bounds__(256) void k_gemm(
    const int* __restrict__ ids1, const float* __restrict__ feats,
    const float* __restrict__ Wx, const float* __restrict__ bx,
    const float* __restrict__ Wn, const float* __restrict__ bn,
    float* __restrict__ m2h1)
{
    __shared__ float a0[BM][IN];
    __shared__ float a1[BM][IN];
    const int tid = threadIdx.x;
    const int r0  = blockIdx.x * BM;

    // staging: 4 rows in parallel (64 thr/row): f1 gather + contiguous m2 row
    const int sub = tid & 63;
    const int rg  = tid >> 6;
    #pragma unroll
    for (int i = 0; i < BM; i += 4) {
        const int rr = rg + i;
        const int r  = r0 + rr;
        ((float4*)a0[rr])[sub] = ((const float4*)(feats + (size_t)ids1[r] * IN))[sub];
        ((float4*)a1[rr])[sub] = ((const float4*)(m2h1 + (size_t)r * IN))[sub];
    }
    __syncthreads();

    // compute: 8 rows x 2 cols per thread
    const int j  = tid & 127;
    const int g  = tid >> 7;            // row group 0..1
    const int c0 = 2 * j;               // output col pair in [0,256)
    const bool nb = (c0 >= HIDC);
    const int cc  = c0 & (HIDC - 1);
    const float  b0 = (nb ? bn : bx)[cc];
    const float  b1 = (nb ? bn : bx)[cc + 1];
    const float (* __restrict__ A)[IN] = nb ? a1 : a0;
    const float2* __restrict__ W2 = (const float2*)(nb ? Wn : Wx);
    const int w2i = cc >> 1;

    float acc0[8], acc1[8];
    #pragma unroll
    for (int rr = 0; rr < 8; ++rr) { acc0[rr] = 0.f; acc1[rr] = 0.f; }

    for (int k = 0; k < IN; k += 4) {
        float4 av[8];
        #pragma unroll
        for (int rr = 0; rr < 8; ++rr)
            av[rr] = *(const float4*)&A[g * 8 + rr][k];   // wave-uniform broadcast
        #pragma unroll
        for (int kk = 0; kk < 4; ++kk) {
            const float2 w = W2[(size_t)(k + kk) * 64 + w2i];
            #pragma unroll
            for (int rr = 0; rr < 8; ++rr) {
                const float a = (&av[rr].x)[kk];
                acc0[rr] = fmaf(a, w.x, acc0[rr]);
                acc1[rr] = fmaf(a, w.y, acc1[rr]);
            }
        }
    }
    __syncthreads();   // all LDS reads done before overwriting m2 rows
    #pragma unroll
    for (int rr = 0; rr < 8; ++rr) {
        const int r = r0 + g * 8 + rr;
        float2 v;
        v.x = fmaxf(acc0[rr] + b0, 0.f);
        v.y = fmaxf(acc1[rr] + b1, 0.f);
        *(float2*)&m2h1[(size_t)r * IN + c0] = v;
    }
}

// ---------------- Kernel C: per output row, 512 threads ---------------------
__global__ __launch_bounds__(512) void k_out(
    const int* __restrict__ ids, const int* __restrict__ ids1,
    const float* __restrict__ feats, const float* __restrict__ h1,
    const float* __restrict__ Wx1, const float* __restrict__ bx1,
    const float* __restrict__ Wn1, const float* __restrict__ bn1,
    const float* __restrict__ Wx2, const float* __restrict__ bx2,
    const float* __restrict__ Wn2, const float* __restrict__ bn2,
    const float* __restrict__ Wfc, const float* __restrict__ bfc,
    float* __restrict__ out)
{
    __shared__ float x0[IN];
    __shared__ float m1[IN];
    __shared__ float mh[IN];
    __shared__ float h0[IN];
    __shared__ float g0[IN];
    __shared__ float partA[2][IN];
    __shared__ float partB[2][IN];
    __shared__ float red[8];
    __shared__ float fcred[7][4];
    const int i   = blockIdx.x;
    const int tid = threadIdx.x;
    const int c   = tid & 255;
    const int h   = tid >> 8;

    float s = 0.f, sh = 0.f;
    for (int kk = h; kk < 25; kk += 2) {
        const int r = i * 25 + kk;
        s  += feats[(size_t)ids1[r] * IN + c];
        sh += h1[(size_t)r * IN + c];
    }
    if (h == 0) x0[c] = feats[(size_t)ids[i] * IN + c];
    partA[h][c] = s;
    partB[h][c] = sh;
    __syncthreads();
    if (h == 0) m1[c] = (partA[0][c] + partA[1][c]) * 0.04f;
    else        mh[c] = (partB[0][c] + partB[1][c]) * 0.04f;
    __syncthreads();

    const int  jj = c & 127;
    const bool nb = (c >= 128);
    {
        const float* __restrict__ W = nb ? Wn1 : Wx1;
        const float* __restrict__ X = nb ? m1 : x0;
        float acc = 0.f;
        #pragma unroll 4
        for (int k = h * 128; k < h * 128 + 128; ++k)
            acc = fmaf(X[k], W[(size_t)k * HIDC + jj], acc);
        partA[h][c] = acc;
    }
    __syncthreads();
    if (h == 0)
        h0[c] = fmaxf(partA[0][c] + partA[1][c] + (nb ? bn1 : bx1)[jj], 0.f);
    __syncthreads();
    {
        const float* __restrict__ W = nb ? Wn2 : Wx2;
        const float* __restrict__ X = nb ? mh : h0;
        float acc = 0.f;
        #pragma unroll 4
        for (int k = h * 128; k < h * 128 + 128; ++k)
            acc = fmaf(X[k], W[(size_t)k * HIDC + jj], acc);
        partB[h][c] = acc;
    }
    __syncthreads();
    if (h == 0)
        g0[c] = partB[0][c] + partB[1][c] + (nb ? bn2 : bx2)[jj];
    __syncthreads();

    {
        const float gv = g0[c];
        float sq = gv * gv;
        #pragma unroll
        for (int off = 32; off > 0; off >>= 1) sq += __shfl_down(sq, off);
        if ((tid & 63) == 0) red[tid >> 6] = sq;
    }
    __syncthreads();
    const float total = (red[0] + red[1] + red[2] + red[3] +
                         red[4] + red[5] + red[6] + red[7]) * 0.5f;
    const float inv = 1.f / fmaxf(sqrtf(total), 1e-12f);
    const float p = g0[c] * inv;

    const int qbase = h * 4;
    const int qn    = h ? 3 : 4;
    for (int q = qbase; q < qbase + qn; ++q) {
        float t = p * Wfc[(size_t)c * 7 + q];
        #pragma unroll
        for (int off = 32; off > 0; off >>= 1) t += __shfl_down(t, off);
        if ((tid & 63) == 0) fcred[q][(tid >> 6) & 3] = t;
    }
    __syncthreads();
    if (tid < 7) {
        out[(size_t)i * 7 + tid] =
            fcred[tid][0] + fcred[tid][1] + fcred[tid][2] + fcred[tid][3] + bfc[tid];
    }
}

extern "C" void kernel_launch(void* const* d_in, const int* in_sizes, int n_in,
                              void* d_out, int out_size, void* d_ws, size_t ws_size,
                              hipStream_t stream) {
    const int*   ids   = (const int*)d_in[0];
    const int*   ids1  = (const int*)d_in[1];
    const int*   ids2  = (const int*)d_in[2];
    const float* feats = (const float*)d_in[3];
    const float* Wx1   = (const float*)d_in[4];
    const float* bx1   = (const float*)d_in[5];
    const float* Wn1   = (const float*)d_in[6];
    const float* bn1   = (const float*)d_in[7];
    const float* Wx2   = (const float*)d_in[8];
    const float* bx2   = (const float*)d_in[9];
    const float* Wn2   = (const float*)d_in[10];
    const float* bn2   = (const float*)d_in[11];
    const float* Wfc   = (const float*)d_in[12];
    const float* bfc   = (const float*)d_in[13];
    float* out  = (float*)d_out;
    float* m2h1 = (float*)d_ws;   // 12800 x 256 f32 = 13.1 MB (m2, then h1 in-place)

    k_mean<<<ROWS1 / 8, 512, 0, stream>>>(ids2, feats, m2h1);
    k_gemm<<<ROWS1 / BM, 256, 0, stream>>>(ids1, feats, Wx1, bx1, Wn1, bn1, m2h1);
    k_out<<<512, 512, 0, stream>>>(ids, ids1, feats, m2h1,
                                   Wx1, bx1, Wn1, bn1,
                                   Wx2, bx2, Wn2, bn2,
                                   Wfc, bfc, out);
}